// Round 8
// baseline (140.824 us; speedup 1.0000x reference)
//
#include <hip/hip_runtime.h>

// MMD loss. N=8192 rows (4096 X + 4096 Y), D=64, f32 in, f32 scalar out.
//   bandwidth: closed form  sum_ij L2 = 2N*sum(sq) - 2*||sum z||^2
//   symmetry: K(i,j)=K(j,i) -> block-upper-triangle, off-diag tiles weight 2.
//   main: dot via bf16 split (hh+hl+lh) MFMA 16x16x32; x4 = s4*L2 (s4=-log2e/(4bw))
//         K5 = v + v^2 + v^4 + v^8 + v^16,  v = 2^min(x4,0)
//   out = (sum_ij sign_i*sign_j*K5_ij) / 4096^2, finalized by last block.

#define NX 4096
#define NT 8192
#define DD 64
#define NBLK 32                 // 256-row macro tiles
#define NTRI (NBLK * (NBLK + 1) / 2)   // 528

using f32x4 = __attribute__((ext_vector_type(4))) float;
using s8v   = __attribute__((ext_vector_type(8))) short;   // 8 bf16 = 4 VGPR

__device__ __forceinline__ float fast_exp2(float x) {
#if __has_builtin(__builtin_amdgcn_exp2f)
    return __builtin_amdgcn_exp2f(x);
#else
    return exp2f(x);
#endif
}
__device__ __forceinline__ ushort f2bf(float f) {          // RTNE f32 -> bf16 bits
    unsigned u = __float_as_uint(f);
    unsigned r = u + 0x7fffu + ((u >> 16) & 1u);
    return (ushort)(r >> 16);
}
__device__ __forceinline__ float bf2f(ushort h) {
    return __uint_as_float((unsigned)h << 16);
}

// ---- fused prep: sq[], sum(sq), colsum[64], bf16 hi/lo split ---------------
// grid 256 x 512: each block handles 32 rows in one shot.
__global__ __launch_bounds__(512)
void k_prep(const float* __restrict__ X, const float* __restrict__ Y,
            ushort* __restrict__ ZH, ushort* __restrict__ ZL,
            float* __restrict__ sq, float* __restrict__ colsum,
            double* __restrict__ sumsq)
{
    const int tid = threadIdx.x, bid = blockIdx.x;
    const int sub = tid & 15;                 // float4 column group

    const int row = bid * 32 + (tid >> 4);
    const float4* zr = (const float4*)((row < NX) ? (X + (size_t)row * DD)
                                                  : (Y + (size_t)(row - NX) * DD));
    float4 v = zr[sub];

    ushort h0 = f2bf(v.x), h1 = f2bf(v.y), h2 = f2bf(v.z), h3 = f2bf(v.w);
    ushort l0 = f2bf(v.x - bf2f(h0)), l1 = f2bf(v.y - bf2f(h1));
    ushort l2 = f2bf(v.z - bf2f(h2)), l3 = f2bf(v.w - bf2f(h3));
    ((ushort4*)(ZH + (size_t)row * DD))[sub] = make_ushort4(h0, h1, h2, h3);
    ((ushort4*)(ZL + (size_t)row * DD))[sub] = make_ushort4(l0, l1, l2, l3);

    float d = fmaf(v.x, v.x, fmaf(v.y, v.y, fmaf(v.z, v.z, v.w * v.w)));
    float dr = d;
#pragma unroll
    for (int m = 1; m < 16; m <<= 1) dr += __shfl_xor(dr, m);
    if (sub == 0) sq[row] = dr;

    // column sums: within a wave, lanes {l, l+16, l+32, l+48} share sub
    float ca0 = v.x, ca1 = v.y, ca2 = v.z, ca3 = v.w;
    ca0 += __shfl_xor(ca0, 16); ca0 += __shfl_xor(ca0, 32);
    ca1 += __shfl_xor(ca1, 16); ca1 += __shfl_xor(ca1, 32);
    ca2 += __shfl_xor(ca2, 16); ca2 += __shfl_xor(ca2, 32);
    ca3 += __shfl_xor(ca3, 16); ca3 += __shfl_xor(ca3, 32);
    __shared__ float colred[64];
    if (tid < 64) colred[tid] = 0.f;
    __syncthreads();
    if ((tid & 63) < 16) {
        atomicAdd(&colred[sub * 4 + 0], ca0);
        atomicAdd(&colred[sub * 4 + 1], ca1);
        atomicAdd(&colred[sub * 4 + 2], ca2);
        atomicAdd(&colred[sub * 4 + 3], ca3);
    }

    float ssq = d;
#pragma unroll
    for (int off = 32; off; off >>= 1) ssq += __shfl_down(ssq, off);
    if ((tid & 63) == 0) atomicAdd(sumsq, (double)ssq);

    __syncthreads();
    if (tid < 64) atomicAdd(&colsum[tid], colred[tid]);
}

// ---- main pairwise pass (block-upper-triangle) -----------------------------
// grid 528: tile (bi,bj), bi<=bj, each 256 i x 256 j; 4 iters of 64-wide j-tiles.
// 8 waves = 4(wr) x 2(wc); wave tile 64 i x 32 j per iter.
struct BFrag { s8v h[2][2]; s8v l[2][2]; };   // [cg][ks]

__global__ __launch_bounds__(512)
void k_main(const ushort* __restrict__ ZH, const ushort* __restrict__ ZL,
            const float* __restrict__ sq, const float* __restrict__ colsum,
            const double* __restrict__ sumsq,
            double* __restrict__ accS, unsigned* __restrict__ cnt,
            float* __restrict__ out)
{
    __shared__ double sred[8];
    const int tid = threadIdx.x, lane = tid & 63, wid = tid >> 6;
    const int wr = wid >> 1, wc = wid & 1;
    const int l15 = lane & 15, lh = lane >> 4;

    // decode upper-triangle tile index (scalar, 32 iters max)
    int t = blockIdx.x, bi = 0;
    while (t >= NBLK - bi) { t -= NBLK - bi; ++bi; }
    const int bj = bi + t;

    const int rbase = bi * 256 + wr * 64;
    const int jbase = bj * 256;

    // bandwidth constants (redundant per wave; colsum/sumsq tiny + cache-hot)
    double cv = (double)colsum[lane]; cv *= cv;
#pragma unroll
    for (int m = 1; m < 64; m <<= 1) cv += __shfl_xor(cv, m);
    const double sl2 = 2.0 * (double)NT * sumsq[0] - 2.0 * cv;
    const double bwv = sl2 / ((double)NT * (double)NT - (double)NT);
    const float s4  = (float)(-0.36067376022224085 / bwv);   // -log2(e)/4 / bw
    const float c2q = -2.0f * s4;

    // A fragments + row-norm terms, cached for the whole tile
    s8v ah[4][2], al[4][2];
    f32x4 psi[4];
#pragma unroll
    for (int rg = 0; rg < 4; ++rg) {
#pragma unroll
        for (int ks = 0; ks < 2; ++ks) {
            size_t off = (size_t)(rbase + rg * 16 + l15) * DD + ks * 32 + lh * 8;
            ah[rg][ks] = *(const s8v*)(ZH + off);
            al[rg][ks] = *(const s8v*)(ZL + off);
        }
        f32x4 sv = *(const f32x4*)(sq + rbase + rg * 16 + lh * 4);
        psi[rg] = s4 * sv;
    }

    double dsum = 0.0;

    auto LOADB = [&](BFrag& b, int tt) {
        const int cb = jbase + tt * 64 + wc * 32;
#pragma unroll
        for (int cg = 0; cg < 2; ++cg)
#pragma unroll
            for (int ks = 0; ks < 2; ++ks) {
                size_t off = (size_t)(cb + cg * 16 + l15) * DD + ks * 32 + lh * 8;
                b.h[cg][ks] = *(const s8v*)(ZH + off);
                b.l[cg][ks] = *(const s8v*)(ZL + off);
            }
    };

    auto STEP = [&](const BFrag& b, int tt) {
        const int cb = jbase + tt * 64 + wc * 32;
        f32x4 acc[4][2];
#pragma unroll
        for (int rg = 0; rg < 4; ++rg)
#pragma unroll
            for (int cg = 0; cg < 2; ++cg)
                acc[rg][cg] = (f32x4){0.f, 0.f, 0.f, 0.f};
#pragma unroll
        for (int ks = 0; ks < 2; ++ks)
#pragma unroll
            for (int rg = 0; rg < 4; ++rg)
#pragma unroll
                for (int cg = 0; cg < 2; ++cg) {
                    acc[rg][cg] = __builtin_amdgcn_mfma_f32_16x16x32_bf16(ah[rg][ks], b.h[cg][ks], acc[rg][cg], 0, 0, 0);
                    acc[rg][cg] = __builtin_amdgcn_mfma_f32_16x16x32_bf16(ah[rg][ks], b.l[cg][ks], acc[rg][cg], 0, 0, 0);
                    acc[rg][cg] = __builtin_amdgcn_mfma_f32_16x16x32_bf16(al[rg][ks], b.h[cg][ks], acc[rg][cg], 0, 0, 0);
                }
        const float sj0 = s4 * sq[cb + l15];
        const float sj1 = s4 * sq[cb + 16 + l15];
        float bsum = 0.f;
#pragma unroll
        for (int rg = 0; rg < 4; ++rg)
#pragma unroll
            for (int cg = 0; cg < 2; ++cg) {
                const float sj = cg ? sj1 : sj0;
#pragma unroll
                for (int q = 0; q < 4; ++q) {
                    float x = fmaf(c2q, acc[rg][cg][q], psi[rg][q] + sj);
                    x = fminf(x, 0.f);                  // clamp(L2,0)
                    float v  = fast_exp2(x);            // u^(1/4)
                    float v2 = v * v, v4 = v2 * v2, v8 = v4 * v4, v16 = v8 * v8;
                    bsum += ((v16 + v8) + (v4 + v2)) + v;
                }
            }
        dsum += (double)bsum;
    };

    BFrag b0, b1;
    LOADB(b0, 0);
#pragma unroll
    for (int tp = 0; tp < 2; ++tp) {
        const int t0 = 2 * tp, t1 = t0 + 1;
        LOADB(b1, t1);
        STEP(b0, t0);
        if (t1 + 1 < 4) LOADB(b0, t1 + 1);
        STEP(b1, t1);
    }

#pragma unroll
    for (int off = 32; off; off >>= 1) dsum += __shfl_down(dsum, off);
    if (lane == 0) sred[wid] = dsum;
    __syncthreads();
    if (tid == 0) {
        double bsum = 0.0;
#pragma unroll
        for (int w = 0; w < 8; ++w) bsum += sred[w];
        const bool pos = (bi < 16) == (bj < 16);        // sign s_i*s_j, tile-uniform
        const double wt = (bi == bj) ? 1.0 : 2.0;       // triangle weight
        atomicAdd(accS, pos ? wt * bsum : -wt * bsum);
        __threadfence();
        unsigned old = atomicAdd(cnt, 1u);
        if (old == (unsigned)NTRI - 1u) {               // last block finalizes
            double S = atomicAdd(accS, 0.0);
            out[0] = (float)(S * (1.0 / ((double)NX * (double)NX)));
        }
    }
}

extern "C" void kernel_launch(void* const* d_in, const int* in_sizes, int n_in,
                              void* d_out, int out_size, void* d_ws, size_t ws_size,
                              hipStream_t stream)
{
    const float* X = (const float*)d_in[0];
    const float* Y = (const float*)d_in[1];

    char* ws = (char*)d_ws;
    double*   sumsq  = (double*)(ws + 0);
    double*   accS   = (double*)(ws + 8);
    unsigned* cnt    = (unsigned*)(ws + 16);
    float*    colsum = (float*)(ws + 64);               // 64 f32
    float*    sq     = (float*)(ws + 512);              // 8192 f32
    ushort*   ZH     = (ushort*)(ws + 65536);           // 1 MB
    ushort*   ZL     = (ushort*)(ws + 65536 + 1048576); // 1 MB

    hipMemsetAsync(d_ws, 0, 512, stream);
    k_prep<<<256, 512, 0, stream>>>(X, Y, ZH, ZL, sq, colsum, sumsq);
    k_main<<<NTRI, 512, 0, stream>>>(ZH, ZL, sq, colsum, sumsq,
                                     accS, cnt, (float*)d_out);
}

// Round 9
// 92.980 us; speedup vs baseline: 1.5146x; 1.5146x over previous
//
#include <hip/hip_runtime.h>

// MMD loss. N=8192 rows (4096 X + 4096 Y), D=64, f32 in, f32 scalar out.
//   bandwidth: closed form  sum_ij L2 = 2N*sum(sq) - 2*||sum z||^2
//   symmetry: block-upper-triangle (256^2 macro tiles), off-diag weight 2.
//   dot in PURE bf16 MFMA 16x16x32 (error ~1e-7 on out, threshold 3.2e-5).
//   x4 = s4*L2; K5 = v+v^2+v^4+v^8+v^16, v = 2^min(x4,0)
//   out = (sum_ij s_i s_j K5_ij)/4096^2, finalized by last k_main block.

#define NX 4096
#define NT 8192
#define DD 64
#define NBLK 32
#define NTRI (NBLK * (NBLK + 1) / 2)   // 528

using f32x4 = __attribute__((ext_vector_type(4))) float;
using s8v   = __attribute__((ext_vector_type(8))) short;   // 8 bf16 = 4 VGPR

__device__ __forceinline__ float fast_exp2(float x) {
#if __has_builtin(__builtin_amdgcn_exp2f)
    return __builtin_amdgcn_exp2f(x);
#else
    return exp2f(x);
#endif
}
__device__ __forceinline__ ushort f2bf(float f) {          // RTNE f32 -> bf16 bits
    unsigned u = __float_as_uint(f);
    unsigned r = u + 0x7fffu + ((u >> 16) & 1u);
    return (ushort)(r >> 16);
}

// ---- prep: bf16 cast, sq[], colsum[64], sumsq -- 64 blocks x 512 -----------
__global__ __launch_bounds__(512)
void k_prep(const float* __restrict__ X, const float* __restrict__ Y,
            ushort* __restrict__ ZH, float* __restrict__ sq,
            float* __restrict__ colsum, double* __restrict__ sumsq)
{
    __shared__ float  colred[64];
    __shared__ double ssred[8];
    const int tid = threadIdx.x, bid = blockIdx.x;
    const int sub = tid & 15;
    if (tid < 64) colred[tid] = 0.f;
    __syncthreads();

    float ca0 = 0.f, ca1 = 0.f, ca2 = 0.f, ca3 = 0.f, ssq = 0.f;
#pragma unroll
    for (int k = 0; k < 4; ++k) {
        const int row = bid * 128 + k * 32 + (tid >> 4);
        const float4* zr = (const float4*)((row < NX) ? (X + (size_t)row * DD)
                                                      : (Y + (size_t)(row - NX) * DD));
        float4 v = zr[sub];
        ((ushort4*)(ZH + (size_t)row * DD))[sub] =
            make_ushort4(f2bf(v.x), f2bf(v.y), f2bf(v.z), f2bf(v.w));
        float d = fmaf(v.x, v.x, fmaf(v.y, v.y, fmaf(v.z, v.z, v.w * v.w)));
        ssq += d;
        float dr = d;
#pragma unroll
        for (int m = 1; m < 16; m <<= 1) dr += __shfl_xor(dr, m);
        if (sub == 0) sq[row] = dr;
        ca0 += v.x; ca1 += v.y; ca2 += v.z; ca3 += v.w;
    }

    // column sums within wave: lanes {l, l+16, l+32, l+48} share sub
    ca0 += __shfl_xor(ca0, 16); ca0 += __shfl_xor(ca0, 32);
    ca1 += __shfl_xor(ca1, 16); ca1 += __shfl_xor(ca1, 32);
    ca2 += __shfl_xor(ca2, 16); ca2 += __shfl_xor(ca2, 32);
    ca3 += __shfl_xor(ca3, 16); ca3 += __shfl_xor(ca3, 32);
    if ((tid & 63) < 16) {
        atomicAdd(&colred[sub * 4 + 0], ca0);
        atomicAdd(&colred[sub * 4 + 1], ca1);
        atomicAdd(&colred[sub * 4 + 2], ca2);
        atomicAdd(&colred[sub * 4 + 3], ca3);
    }
#pragma unroll
    for (int off = 32; off; off >>= 1) ssq += __shfl_down(ssq, off);
    if ((tid & 63) == 0) ssred[tid >> 6] = (double)ssq;
    __syncthreads();
    if (tid == 0) {
        double s = 0.0;
#pragma unroll
        for (int w = 0; w < 8; ++w) s += ssred[w];
        atomicAdd(sumsq, s);                       // 64 atomics total
    }
    if (tid < 64) atomicAdd(&colsum[tid], colred[tid]);
}

// ---- bandwidth constants (1 wave) ------------------------------------------
__global__ void k_bw(const double* __restrict__ sumsq, const float* __restrict__ colsum,
                     float* __restrict__ cs)
{
    const int lane = threadIdx.x;
    double cv = (double)colsum[lane]; cv *= cv;
#pragma unroll
    for (int m = 1; m < 64; m <<= 1) cv += __shfl_xor(cv, m);
    if (lane == 0) {
        double sl2 = 2.0 * (double)NT * sumsq[0] - 2.0 * cv;
        double bw = sl2 / ((double)NT * (double)NT - (double)NT);
        double s4 = -0.36067376022224085 / bw;     // -log2(e)/4 / bw
        cs[0] = (float)s4;
        cs[1] = (float)(-2.0 * s4);
    }
}

// ---- main pairwise pass (block-upper-triangle) -----------------------------
// grid 528: tile (bi,bj) bi<=bj, 256x256; 4 j-steps of 64.
// 8 waves = 4(wr) x 2(wc); wave tile 64 i x 32 j per step.
struct BFrag { s8v h[2][2]; };   // [cg][ks]

__global__ __launch_bounds__(512, 4)   // cap ~128 VGPR -> 2 blocks/CU
void k_main(const ushort* __restrict__ ZH, const float* __restrict__ sq,
            const float* __restrict__ cs,
            double* __restrict__ accS, unsigned* __restrict__ cnt,
            float* __restrict__ out)
{
    __shared__ double sred[8];
    const int tid = threadIdx.x, lane = tid & 63, wid = tid >> 6;
    const int wr = wid >> 1, wc = wid & 1;
    const int l15 = lane & 15, lh = lane >> 4;

    int t = blockIdx.x, bi = 0;                    // triangle decode
    while (t >= NBLK - bi) { t -= NBLK - bi; ++bi; }
    const int bj = bi + t;

    const int rbase = bi * 256 + wr * 64;
    const int jbase = bj * 256;
    const float s4 = cs[0], c2q = cs[1];

    // A fragments + row-norm terms, cached for the whole tile
    s8v ah[4][2];
    f32x4 psi[4];
#pragma unroll
    for (int rg = 0; rg < 4; ++rg) {
#pragma unroll
        for (int ks = 0; ks < 2; ++ks)
            ah[rg][ks] = *(const s8v*)(ZH + (size_t)(rbase + rg * 16 + l15) * DD + ks * 32 + lh * 8);
        psi[rg] = s4 * (*(const f32x4*)(sq + rbase + rg * 16 + lh * 4));
    }

    double dsum = 0.0;

    auto LOADB = [&](BFrag& b, int tt) {
        const int cb = jbase + tt * 64 + wc * 32;
#pragma unroll
        for (int cg = 0; cg < 2; ++cg)
#pragma unroll
            for (int ks = 0; ks < 2; ++ks)
                b.h[cg][ks] = *(const s8v*)(ZH + (size_t)(cb + cg * 16 + l15) * DD + ks * 32 + lh * 8);
    };

    auto STEP = [&](const BFrag& b, int tt) {
        const int cb = jbase + tt * 64 + wc * 32;
        f32x4 acc[4][2];
#pragma unroll
        for (int rg = 0; rg < 4; ++rg)
#pragma unroll
            for (int cg = 0; cg < 2; ++cg)
                acc[rg][cg] = (f32x4){0.f, 0.f, 0.f, 0.f};
#pragma unroll
        for (int ks = 0; ks < 2; ++ks)
#pragma unroll
            for (int rg = 0; rg < 4; ++rg)
#pragma unroll
                for (int cg = 0; cg < 2; ++cg)
                    acc[rg][cg] = __builtin_amdgcn_mfma_f32_16x16x32_bf16(
                        ah[rg][ks], b.h[cg][ks], acc[rg][cg], 0, 0, 0);
        const float sj0 = s4 * sq[cb + l15];
        const float sj1 = s4 * sq[cb + 16 + l15];
        float bsum = 0.f;
#pragma unroll
        for (int rg = 0; rg < 4; ++rg)
#pragma unroll
            for (int cg = 0; cg < 2; ++cg) {
                const float sj = cg ? sj1 : sj0;
#pragma unroll
                for (int q = 0; q < 4; ++q) {
                    float x = fmaf(c2q, acc[rg][cg][q], psi[rg][q] + sj);
                    x = fminf(x, 0.f);              // clamp(L2,0)
                    float v  = fast_exp2(x);        // u^(1/4)
                    float v2 = v * v, v4 = v2 * v2, v8 = v4 * v4, v16 = v8 * v8;
                    bsum += ((v16 + v8) + (v4 + v2)) + v;
                }
            }
        dsum += (double)bsum;
    };

    BFrag b0, b1;
    LOADB(b0, 0);
    LOADB(b1, 1);
    STEP(b0, 0);
    LOADB(b0, 2);
    STEP(b1, 1);
    LOADB(b1, 3);
    STEP(b0, 2);
    STEP(b1, 3);

#pragma unroll
    for (int off = 32; off; off >>= 1) dsum += __shfl_down(dsum, off);
    if (lane == 0) sred[wid] = dsum;
    __syncthreads();
    if (tid == 0) {
        double bsum = 0.0;
#pragma unroll
        for (int w = 0; w < 8; ++w) bsum += sred[w];
        const bool pos = (bi < 16) == (bj < 16);    // sign s_i*s_j, tile-uniform
        const double wt = (bi == bj) ? 1.0 : 2.0;   // triangle weight
        atomicAdd(accS, pos ? wt * bsum : -wt * bsum);
        __threadfence();
        unsigned old = atomicAdd(cnt, 1u);
        if (old == (unsigned)NTRI - 1u) {           // last block finalizes
            double S = atomicAdd(accS, 0.0);
            out[0] = (float)(S * (1.0 / ((double)NX * (double)NX)));
        }
    }
}

extern "C" void kernel_launch(void* const* d_in, const int* in_sizes, int n_in,
                              void* d_out, int out_size, void* d_ws, size_t ws_size,
                              hipStream_t stream)
{
    const float* X = (const float*)d_in[0];
    const float* Y = (const float*)d_in[1];

    char* ws = (char*)d_ws;
    double*   sumsq  = (double*)(ws + 0);
    double*   accS   = (double*)(ws + 8);
    unsigned* cnt    = (unsigned*)(ws + 16);
    float*    cs     = (float*)(ws + 24);               // 2 f32
    float*    colsum = (float*)(ws + 64);               // 64 f32
    float*    sq     = (float*)(ws + 512);              // 8192 f32
    ushort*   ZH     = (ushort*)(ws + 65536);           // 1 MB

    hipMemsetAsync(d_ws, 0, 512, stream);
    k_prep<<<64, 512, 0, stream>>>(X, Y, ZH, sq, colsum, sumsq);
    k_bw  <<<1, 64, 0, stream>>>(sumsq, colsum, cs);
    k_main<<<NTRI, 512, 0, stream>>>(ZH, sq, cs, accS, cnt, (float*)d_out);
}